// Round 4
// baseline (603.411 us; speedup 1.0000x reference)
//
#include <hip/hip_runtime.h>
#include <math.h>

// NoisyTokenChoiceRouter: N=16384 tokens, D=2048, E=64 experts, top-k=2.
// Outputs (concatenated fp32 in d_out):
//   [0, 2N)      top_k_values (normalized noisy gates, descending)
//   [2N, 4N)     top_k_indices (written as float(idx))
//   [4N]         aux_loss scalar
//
// R4: same structure as R3 (independent waves, lane==expert, full-D fmaf
// chain per token -- BITWISE-EXACT summation order, do not reorder; R2's
// reorder flipped near-tie top-2 indices). Change: TOK 4->2, grid 2048,
// __launch_bounds__(256,8) -> 8192 waves = 32/CU (HW max), to hide the
// ~500-cycle L3 latency on the scalar x stream (R3: VALUBusy 23%,
// occupancy 34%, stall arithmetic matched L3-latency-bound).
#define NTOK 16384
#define DDIM 2048
#define NEXP 64
#define TOK  2            // tokens per wave
#define WPB  4            // independent waves per block
#define NBUCKET 32        // hierarchical-atomic buckets for aux partial sums

__device__ __forceinline__ float wave_sum64(float v) {
  #pragma unroll
  for (int off = 32; off > 0; off >>= 1) v += __shfl_xor(v, off, 64);
  return v;
}

__device__ __forceinline__ float wave_max64(float v) {
  #pragma unroll
  for (int off = 32; off > 0; off >>= 1) v = fmaxf(v, __shfl_xor(v, off, 64));
  return v;
}

// max with lowest-index tie-break (matches jax.lax.top_k stability)
__device__ __forceinline__ void wave_argmax64(float &v, int &idx) {
  #pragma unroll
  for (int off = 32; off > 0; off >>= 1) {
    float ov = __shfl_xor(v, off, 64);
    int   oi = __shfl_xor(idx, off, 64);
    if (ov > v || (ov == v && oi < idx)) { v = ov; idx = oi; }
  }
}

__global__ __launch_bounds__(256, 8) void router_main(
    const float* __restrict__ x, const float* __restrict__ W,
    const float* __restrict__ b, const float* __restrict__ noise,
    float* __restrict__ out, float* __restrict__ imp_part,
    float* __restrict__ load_part) {
  const int lane = threadIdx.x & 63;              // lane == expert index
  const int wid  = threadIdx.x >> 6;              // independent wave id
  const int gwave = blockIdx.x * WPB + wid;
  const int token0 = gwave * TOK;                 // wave-uniform
  const float bias = b[lane];

  float acc[TOK];
  #pragma unroll
  for (int t = 0; t < TOK; ++t) acc[t] = 0.0f;

  const float* xr = x + (size_t)token0 * DDIM;

  // matmul: lane e accumulates logits for TOK tokens, column e of W.
  // W row (256B) coalesced per d (L2-hot). x loads wave-uniform -> scalar
  // path (L3-latency ~500cy, hidden by 8 waves/SIMD).
  // INVARIANT: per-token fmaf chain order == round 1 (bitwise-exact logits).
  #pragma unroll 4
  for (int d = 0; d < DDIM; d += 4) {
    const float w0 = W[(size_t)(d + 0) * NEXP + lane];
    const float w1 = W[(size_t)(d + 1) * NEXP + lane];
    const float w2 = W[(size_t)(d + 2) * NEXP + lane];
    const float w3 = W[(size_t)(d + 3) * NEXP + lane];
    #pragma unroll
    for (int t = 0; t < TOK; ++t) {
      const float4 xv = *reinterpret_cast<const float4*>(xr + (size_t)t * DDIM + d);
      acc[t] = fmaf(xv.x, w0, acc[t]);
      acc[t] = fmaf(xv.y, w1, acc[t]);
      acc[t] = fmaf(xv.z, w2, acc[t]);
      acc[t] = fmaf(xv.w, w3, acc[t]);
    }
  }

  const float noise_std = 1.0f / (float)NEXP;
  const float inv_noise = (float)NEXP;
  const float inv_sqrt2 = 0.70710678118654752440f;

  float imp_acc = 0.0f, load_acc = 0.0f;

  #pragma unroll
  for (int t = 0; t < TOK; ++t) {
    const int token = token0 + t;
    const float logit = acc[t] + bias;

    // clean softmax -> importance accumulation
    const float m = wave_max64(logit);
    const float ex = expf(logit - m);
    const float Z = wave_sum64(ex);
    imp_acc += ex / Z;

    // noisy logits
    const float noisy = fmaf(noise[(size_t)token * NEXP + lane], noise_std, logit);

    // top-2 (indices identical for gates_noisy: softmax is monotonic)
    float v1 = noisy; int i1 = lane;
    wave_argmax64(v1, i1);
    float masked = (lane == i1) ? -INFINITY : noisy;
    float v2 = masked; int i2 = lane;
    wave_argmax64(v2, i2);

    // noisy softmax
    const float exn = expf(noisy - v1);
    const float Zn = wave_sum64(exn);
    const float g1 = 1.0f / Zn;
    const float g2 = expf(v2 - v1) / Zn;
    const float s = g1 + g2 + 1e-20f;

    if (lane == 0) {
      out[(size_t)token * 2 + 0] = g1 / s;
      out[(size_t)token * 2 + 1] = g2 / s;
      out[(size_t)NTOK * 2 + (size_t)token * 2 + 0] = (float)i1;
      out[(size_t)NTOK * 2 + (size_t)token * 2 + 1] = (float)i2;
    }

    // load loss: p = 1 - Phi((threshold - logit)/noise_std), threshold = v2
    const float z = (v2 - logit) * inv_noise;
    const float p = 1.0f - 0.5f * (1.0f + erff(z * inv_sqrt2));
    load_acc += p;
  }

  const int bucket = gwave & (NBUCKET - 1);
  atomicAdd(&imp_part[bucket * NEXP + lane], imp_acc);
  atomicAdd(&load_part[bucket * NEXP + lane], load_acc);
}

__global__ __launch_bounds__(64) void router_aux(
    const float* __restrict__ imp_part, const float* __restrict__ load_part,
    float* __restrict__ out) {
  const int lane = threadIdx.x;
  float imp = 0.0f, ld = 0.0f;
  #pragma unroll
  for (int k = 0; k < NBUCKET; ++k) {
    imp += imp_part[k * NEXP + lane];
    ld  += load_part[k * NEXP + lane];
  }
  ld *= 1.0f / (float)NTOK;   // p_mean

  const float mean_i = wave_sum64(imp) * (1.0f / (float)NEXP);
  const float di = imp - mean_i;
  const float var_i = wave_sum64(di * di) * (1.0f / (float)(NEXP - 1));
  const float cv_i = sqrtf(var_i) / (mean_i + 1e-8f);

  const float mean_l = wave_sum64(ld) * (1.0f / (float)NEXP);
  const float dl = ld - mean_l;
  const float var_l = wave_sum64(dl * dl) * (1.0f / (float)(NEXP - 1));
  const float cv_l = sqrtf(var_l) / (mean_l + 1e-8f);

  if (lane == 0) out[(size_t)NTOK * 4] = 0.5f * (cv_i * cv_i + cv_l * cv_l);
}

extern "C" void kernel_launch(void* const* d_in, const int* in_sizes, int n_in,
                              void* d_out, int out_size, void* d_ws, size_t ws_size,
                              hipStream_t stream) {
  const float* x     = (const float*)d_in[0];
  const float* W     = (const float*)d_in[1];
  const float* b     = (const float*)d_in[2];
  const float* noise = (const float*)d_in[3];
  float* out = (float*)d_out;

  float* imp_part  = (float*)d_ws;                 // [NBUCKET][NEXP]
  float* load_part = imp_part + NBUCKET * NEXP;    // [NBUCKET][NEXP]

  hipMemsetAsync(d_ws, 0, 2 * NBUCKET * NEXP * sizeof(float), stream);
  router_main<<<NTOK / (TOK * WPB), 256, 0, stream>>>(x, W, b, noise, out,
                                                      imp_part, load_part);
  router_aux<<<1, 64, 0, stream>>>(imp_part, load_part, out);
}

// Round 6
// 513.239 us; speedup vs baseline: 1.1757x; 1.1757x over previous
//
#include <hip/hip_runtime.h>
#include <math.h>

// NoisyTokenChoiceRouter: N=16384 tokens, D=2048, E=64 experts, top-k=2.
// Outputs (concatenated fp32 in d_out):
//   [0, 2N)      top_k_values (normalized noisy gates, descending)
//   [2N, 4N)     top_k_indices (written as float(idx))
//   [4N]         aux_loss scalar
//
// R6 == R5 resubmitted (round 5 was a GPU-acquisition infra failure; kernel
// never ran). Rationale below unchanged.
//
// R5: block = 4 waves; W shared across waves via double-buffered LDS tiles
// (KC=64 rows -> 16KB/buf, 32KB total). Cuts W L2 traffic 4x (waves x 512KB
// -> blocks x 512KB). Each wave owns TOK=4 tokens; per-token fmaf chain
// remains BITWISE-IDENTICAL to R1/R3 (W bits unchanged through LDS, same
// ascending-d order) -- R2 proved reordering flips near-tie top-2 indices.
// LDS W reads: addr = dd*64+lane -> bank lane%32 -> 2 lanes/bank = free.
// R4 lesson: do NOT clamp VGPRs below the unrolled body's load window
// ((256,8) forced VGPR=32, serialized loads, 378->454us). Cap at 128
// ((256,4) -> 16 waves/CU) instead.
#define NTOK 16384
#define DDIM 2048
#define NEXP 64
#define TOK  4            // tokens per wave
#define WPB  4            // waves per block
#define KC   64           // W rows per LDS chunk
#define NCHUNK (DDIM / KC)
#define NBUCKET 32

__device__ __forceinline__ float wave_sum64(float v) {
  #pragma unroll
  for (int off = 32; off > 0; off >>= 1) v += __shfl_xor(v, off, 64);
  return v;
}

__device__ __forceinline__ float wave_max64(float v) {
  #pragma unroll
  for (int off = 32; off > 0; off >>= 1) v = fmaxf(v, __shfl_xor(v, off, 64));
  return v;
}

// max with lowest-index tie-break (matches jax.lax.top_k stability)
__device__ __forceinline__ void wave_argmax64(float &v, int &idx) {
  #pragma unroll
  for (int off = 32; off > 0; off >>= 1) {
    float ov = __shfl_xor(v, off, 64);
    int   oi = __shfl_xor(idx, off, 64);
    if (ov > v || (ov == v && oi < idx)) { v = ov; idx = oi; }
  }
}

__global__ __launch_bounds__(256, 4) void router_main(
    const float* __restrict__ x, const float* __restrict__ W,
    const float* __restrict__ b, const float* __restrict__ noise,
    float* __restrict__ out, float* __restrict__ imp_part,
    float* __restrict__ load_part) {
  const int lane = threadIdx.x & 63;              // lane == expert index
  const int wid  = threadIdx.x >> 6;
  const int token0 = (blockIdx.x * WPB + wid) * TOK;  // wave-uniform

  __shared__ float ldsW[2][KC * NEXP];            // 2 x 16KB

  float acc[TOK];
  #pragma unroll
  for (int t = 0; t < TOK; ++t) acc[t] = 0.0f;

  const float* xr = x + (size_t)token0 * DDIM;

  // ---- stage chunk 0 ----
  #pragma unroll
  for (int j = 0; j < 4; ++j) {
    const int f = j * 256 + threadIdx.x;          // float4 index in 16KB tile
    *reinterpret_cast<float4*>(&ldsW[0][f * 4]) =
        *reinterpret_cast<const float4*>(&W[(size_t)f * 4]);
  }
  __syncthreads();

  for (int kc = 0; kc < NCHUNK; ++kc) {
    const int cur = kc & 1;
    // issue next-chunk staging loads first (overlap with compute; the
    // end-of-iteration barrier's vmcnt drain publishes them)
    if (kc + 1 < NCHUNK) {
      #pragma unroll
      for (int j = 0; j < 4; ++j) {
        const int f = j * 256 + threadIdx.x;
        *reinterpret_cast<float4*>(&ldsW[cur ^ 1][f * 4]) =
            *reinterpret_cast<const float4*>(
                &W[(size_t)(kc + 1) * KC * NEXP + (size_t)f * 4]);
      }
    }
    // compute on current chunk: same ascending-d fmaf order as R1/R3
    const int d0 = kc * KC;
    #pragma unroll 4
    for (int dd = 0; dd < KC; dd += 4) {
      const float w0 = ldsW[cur][(dd + 0) * NEXP + lane];
      const float w1 = ldsW[cur][(dd + 1) * NEXP + lane];
      const float w2 = ldsW[cur][(dd + 2) * NEXP + lane];
      const float w3 = ldsW[cur][(dd + 3) * NEXP + lane];
      #pragma unroll
      for (int t = 0; t < TOK; ++t) {
        const float4 xv = *reinterpret_cast<const float4*>(
            xr + (size_t)t * DDIM + d0 + dd);
        acc[t] = fmaf(xv.x, w0, acc[t]);
        acc[t] = fmaf(xv.y, w1, acc[t]);
        acc[t] = fmaf(xv.z, w2, acc[t]);
        acc[t] = fmaf(xv.w, w3, acc[t]);
      }
    }
    __syncthreads();   // publishes stage(kc+1); protects buf[cur] overwrite
  }

  const float bias = b[lane];
  const float noise_std = 1.0f / (float)NEXP;
  const float inv_noise = (float)NEXP;
  const float inv_sqrt2 = 0.70710678118654752440f;

  float imp_acc = 0.0f, load_acc = 0.0f;

  #pragma unroll
  for (int t = 0; t < TOK; ++t) {
    const int token = token0 + t;
    const float logit = acc[t] + bias;

    // clean softmax -> importance accumulation
    const float m = wave_max64(logit);
    const float ex = expf(logit - m);
    const float Z = wave_sum64(ex);
    imp_acc += ex / Z;

    // noisy logits
    const float noisy = fmaf(noise[(size_t)token * NEXP + lane], noise_std, logit);

    // top-2 (indices identical for gates_noisy: softmax is monotonic)
    float v1 = noisy; int i1 = lane;
    wave_argmax64(v1, i1);
    float masked = (lane == i1) ? -INFINITY : noisy;
    float v2 = masked; int i2 = lane;
    wave_argmax64(v2, i2);

    // noisy softmax
    const float exn = expf(noisy - v1);
    const float Zn = wave_sum64(exn);
    const float g1 = 1.0f / Zn;
    const float g2 = expf(v2 - v1) / Zn;
    const float s = g1 + g2 + 1e-20f;

    if (lane == 0) {
      out[(size_t)token * 2 + 0] = g1 / s;
      out[(size_t)token * 2 + 1] = g2 / s;
      out[(size_t)NTOK * 2 + (size_t)token * 2 + 0] = (float)i1;
      out[(size_t)NTOK * 2 + (size_t)token * 2 + 1] = (float)i2;
    }

    // load loss: p = 1 - Phi((threshold - logit)/noise_std), threshold = v2
    const float z = (v2 - logit) * inv_noise;
    const float p = 1.0f - 0.5f * (1.0f + erff(z * inv_sqrt2));
    load_acc += p;
  }

  const int bucket = (blockIdx.x * WPB + wid) & (NBUCKET - 1);
  atomicAdd(&imp_part[bucket * NEXP + lane], imp_acc);
  atomicAdd(&load_part[bucket * NEXP + lane], load_acc);
}

__global__ __launch_bounds__(64) void router_aux(
    const float* __restrict__ imp_part, const float* __restrict__ load_part,
    float* __restrict__ out) {
  const int lane = threadIdx.x;
  float imp = 0.0f, ld = 0.0f;
  #pragma unroll
  for (int k = 0; k < NBUCKET; ++k) {
    imp += imp_part[k * NEXP + lane];
    ld  += load_part[k * NEXP + lane];
  }
  ld *= 1.0f / (float)NTOK;   // p_mean

  const float mean_i = wave_sum64(imp) * (1.0f / (float)NEXP);
  const float di = imp - mean_i;
  const float var_i = wave_sum64(di * di) * (1.0f / (float)(NEXP - 1));
  const float cv_i = sqrtf(var_i) / (mean_i + 1e-8f);

  const float mean_l = wave_sum64(ld) * (1.0f / (float)NEXP);
  const float dl = ld - mean_l;
  const float var_l = wave_sum64(dl * dl) * (1.0f / (float)(NEXP - 1));
  const float cv_l = sqrtf(var_l) / (mean_l + 1e-8f);

  if (lane == 0) out[(size_t)NTOK * 4] = 0.5f * (cv_i * cv_i + cv_l * cv_l);
}

extern "C" void kernel_launch(void* const* d_in, const int* in_sizes, int n_in,
                              void* d_out, int out_size, void* d_ws, size_t ws_size,
                              hipStream_t stream) {
  const float* x     = (const float*)d_in[0];
  const float* W     = (const float*)d_in[1];
  const float* b     = (const float*)d_in[2];
  const float* noise = (const float*)d_in[3];
  float* out = (float*)d_out;

  float* imp_part  = (float*)d_ws;                 // [NBUCKET][NEXP]
  float* load_part = imp_part + NBUCKET * NEXP;    // [NBUCKET][NEXP]

  hipMemsetAsync(d_ws, 0, 2 * NBUCKET * NEXP * sizeof(float), stream);
  router_main<<<NTOK / (TOK * WPB), 256, 0, stream>>>(x, W, b, noise, out,
                                                      imp_part, load_part);
  router_aux<<<1, 64, 0, stream>>>(imp_part, load_part, out);
}

// Round 7
// 332.142 us; speedup vs baseline: 1.8167x; 1.5452x over previous
//
#include <hip/hip_runtime.h>
#include <math.h>

// NoisyTokenChoiceRouter: N=16384 tokens, D=2048, E=64 experts, top-k=2.
// Outputs (concatenated fp32 in d_out):
//   [0, 2N)      top_k_values (normalized noisy gates, descending)
//   [2N, 4N)     top_k_indices (written as float(idx))
//   [4N]         aux_loss scalar
//
// R7: kill the lgkmcnt-mixing stall. R3-R6 kept x on the SCALAR path
// (s_load, lgkmcnt, out-of-order) which forces coarse lgkmcnt(0) drains
// whenever ds_read/W-LDS ops are also outstanding -> ~500cy stall per
// 128cy body -> per-SIMD VALU ~7.5%. Now BOTH x and W are staged into
// LDS via __builtin_amdgcn_global_load_lds (vmcnt, drained once per
// chunk at the barrier); the hot loop is pure ds_read + fmaf, which the
// compiler pipelines with fine lgkmcnt(N).
//   - W LDS reads: dword addr dd*64+lane -> bank lane%32 -> 2-way = free.
//   - x LDS reads: wave-uniform address -> HW broadcast, conflict-free.
// BITWISE INVARIANT (R2 lesson): per-token fmaf chain walks d=0..2047
// ascending in xyzw order, bits unchanged through LDS -> logits identical
// to R1/R3/R6 (absmax 0.0); do not reorder.
// R4 lesson: gentle launch_bounds (256,3); do not strangle VGPRs.
#define NTOK 16384
#define DDIM 2048
#define NEXP 64
#define TOK  8            // tokens per wave
#define WPB  4            // waves per block
#define TOKPB (TOK * WPB) // 32 tokens per block
#define KC   64           // d-rows per LDS chunk
#define NCHUNK (DDIM / KC)
#define NBUCKET 32

__device__ __forceinline__ float wave_sum64(float v) {
  #pragma unroll
  for (int off = 32; off > 0; off >>= 1) v += __shfl_xor(v, off, 64);
  return v;
}

__device__ __forceinline__ float wave_max64(float v) {
  #pragma unroll
  for (int off = 32; off > 0; off >>= 1) v = fmaxf(v, __shfl_xor(v, off, 64));
  return v;
}

// max with lowest-index tie-break (matches jax.lax.top_k stability)
__device__ __forceinline__ void wave_argmax64(float &v, int &idx) {
  #pragma unroll
  for (int off = 32; off > 0; off >>= 1) {
    float ov = __shfl_xor(v, off, 64);
    int   oi = __shfl_xor(idx, off, 64);
    if (ov > v || (ov == v && oi < idx)) { v = ov; idx = oi; }
  }
}

__device__ __forceinline__ void gload_lds16(const float* g, float* l) {
  __builtin_amdgcn_global_load_lds(
      (const __attribute__((address_space(1))) void*)g,
      (__attribute__((address_space(3))) void*)l, 16, 0, 0);
}
__device__ __forceinline__ void gload_lds4(const float* g, float* l) {
  __builtin_amdgcn_global_load_lds(
      (const __attribute__((address_space(1))) void*)g,
      (__attribute__((address_space(3))) void*)l, 4, 0, 0);
}

__global__ __launch_bounds__(256, 3) void router_main(
    const float* __restrict__ x, const float* __restrict__ W,
    const float* __restrict__ b, const float* __restrict__ noise,
    float* __restrict__ out, float* __restrict__ imp_part,
    float* __restrict__ load_part) {
  const int lane = threadIdx.x & 63;              // lane == expert index
  const int wid  = threadIdx.x >> 6;
  const int token0 = (blockIdx.x * WPB + wid) * TOK;  // this wave's tokens

  __shared__ float ldsW[2][KC * NEXP];            // 2 x 16KB, [d][e] row-major
  __shared__ float ldsX[2][TOKPB * KC];           // 2 x 8KB,  [tok_in_blk][d]

  // stage chunk kc into buffer buf (async, vmcnt; published by barrier).
  // W: wave stages rows wid*16+j*4..+3 (4 rows = 1KB = 64 lanes x 16B).
  // x: wave stages its own TOK token-rows (256B = 64 lanes x 4B each).
  auto stage = [&](int buf, int kc) {
    #pragma unroll
    for (int j = 0; j < 4; ++j) {
      const int row = wid * 16 + j * 4;
      gload_lds16(W + ((size_t)kc * KC + row) * NEXP + lane * 4,
                  &ldsW[buf][row * NEXP]);
    }
    #pragma unroll
    for (int tt = 0; tt < TOK; ++tt) {
      gload_lds4(x + (size_t)(token0 + tt) * DDIM + (size_t)kc * KC + lane,
                 &ldsX[buf][(wid * TOK + tt) * KC]);
    }
  };

  float acc[TOK];
  #pragma unroll
  for (int t = 0; t < TOK; ++t) acc[t] = 0.0f;

  stage(0, 0);
  __syncthreads();

  for (int kc = 0; kc < NCHUNK; ++kc) {
    const int cur = kc & 1;
    if (kc + 1 < NCHUNK) stage(cur ^ 1, kc + 1);  // overlap with compute
    // hot loop: pure LDS + fmaf. Same ascending-d chain as R1/R3/R6.
    #pragma unroll 4
    for (int dd = 0; dd < KC; dd += 4) {
      const float w0 = ldsW[cur][(dd + 0) * NEXP + lane];
      const float w1 = ldsW[cur][(dd + 1) * NEXP + lane];
      const float w2 = ldsW[cur][(dd + 2) * NEXP + lane];
      const float w3 = ldsW[cur][(dd + 3) * NEXP + lane];
      #pragma unroll
      for (int t = 0; t < TOK; ++t) {
        const float4 xv = *reinterpret_cast<const float4*>(
            &ldsX[cur][(wid * TOK + t) * KC + dd]);   // uniform -> broadcast
        acc[t] = fmaf(xv.x, w0, acc[t]);
        acc[t] = fmaf(xv.y, w1, acc[t]);
        acc[t] = fmaf(xv.z, w2, acc[t]);
        acc[t] = fmaf(xv.w, w3, acc[t]);
      }
    }
    __syncthreads();  // publishes stage(kc+1); protects buf[cur] overwrite
  }

  const float bias = b[lane];
  const float noise_std = 1.0f / (float)NEXP;
  const float inv_noise = (float)NEXP;
  const float inv_sqrt2 = 0.70710678118654752440f;

  float imp_acc = 0.0f, load_acc = 0.0f;

  #pragma unroll
  for (int t = 0; t < TOK; ++t) {
    const int token = token0 + t;
    const float logit = acc[t] + bias;

    // clean softmax -> importance accumulation
    const float m = wave_max64(logit);
    const float ex = expf(logit - m);
    const float Z = wave_sum64(ex);
    imp_acc += ex / Z;

    // noisy logits
    const float noisy = fmaf(noise[(size_t)token * NEXP + lane], noise_std, logit);

    // top-2 (indices identical for gates_noisy: softmax is monotonic)
    float v1 = noisy; int i1 = lane;
    wave_argmax64(v1, i1);
    float masked = (lane == i1) ? -INFINITY : noisy;
    float v2 = masked; int i2 = lane;
    wave_argmax64(v2, i2);

    // noisy softmax
    const float exn = expf(noisy - v1);
    const float Zn = wave_sum64(exn);
    const float g1 = 1.0f / Zn;
    const float g2 = expf(v2 - v1) / Zn;
    const float s = g1 + g2 + 1e-20f;

    if (lane == 0) {
      out[(size_t)token * 2 + 0] = g1 / s;
      out[(size_t)token * 2 + 1] = g2 / s;
      out[(size_t)NTOK * 2 + (size_t)token * 2 + 0] = (float)i1;
      out[(size_t)NTOK * 2 + (size_t)token * 2 + 1] = (float)i2;
    }

    // load loss: p = 1 - Phi((threshold - logit)/noise_std), threshold = v2
    const float z = (v2 - logit) * inv_noise;
    const float p = 1.0f - 0.5f * (1.0f + erff(z * inv_sqrt2));
    load_acc += p;
  }

  const int bucket = (blockIdx.x * WPB + wid) & (NBUCKET - 1);
  atomicAdd(&imp_part[bucket * NEXP + lane], imp_acc);
  atomicAdd(&load_part[bucket * NEXP + lane], load_acc);
}

__global__ __launch_bounds__(64) void router_aux(
    const float* __restrict__ imp_part, const float* __restrict__ load_part,
    float* __restrict__ out) {
  const int lane = threadIdx.x;
  float imp = 0.0f, ld = 0.0f;
  #pragma unroll
  for (int k = 0; k < NBUCKET; ++k) {
    imp += imp_part[k * NEXP + lane];
    ld  += load_part[k * NEXP + lane];
  }
  ld *= 1.0f / (float)NTOK;   // p_mean

  const float mean_i = wave_sum64(imp) * (1.0f / (float)NEXP);
  const float di = imp - mean_i;
  const float var_i = wave_sum64(di * di) * (1.0f / (float)(NEXP - 1));
  const float cv_i = sqrtf(var_i) / (mean_i + 1e-8f);

  const float mean_l = wave_sum64(ld) * (1.0f / (float)NEXP);
  const float dl = ld - mean_l;
  const float var_l = wave_sum64(dl * dl) * (1.0f / (float)(NEXP - 1));
  const float cv_l = sqrtf(var_l) / (mean_l + 1e-8f);

  if (lane == 0) out[(size_t)NTOK * 4] = 0.5f * (cv_i * cv_i + cv_l * cv_l);
}

extern "C" void kernel_launch(void* const* d_in, const int* in_sizes, int n_in,
                              void* d_out, int out_size, void* d_ws, size_t ws_size,
                              hipStream_t stream) {
  const float* x     = (const float*)d_in[0];
  const float* W     = (const float*)d_in[1];
  const float* b     = (const float*)d_in[2];
  const float* noise = (const float*)d_in[3];
  float* out = (float*)d_out;

  float* imp_part  = (float*)d_ws;                 // [NBUCKET][NEXP]
  float* load_part = imp_part + NBUCKET * NEXP;    // [NBUCKET][NEXP]

  hipMemsetAsync(d_ws, 0, 2 * NBUCKET * NEXP * sizeof(float), stream);
  router_main<<<NTOK / TOKPB, 256, 0, stream>>>(x, W, b, noise, out,
                                                imp_part, load_part);
  router_aux<<<1, 64, 0, stream>>>(imp_part, load_part, out);
}